// Round 6
// baseline (1517.201 us; speedup 1.0000x reference)
//
#include <hip/hip_runtime.h>

// LSTM, B=512 x T=1024, H=100, input_size=1.  MFMA persistent-RNN.
//
// R5 post-mortem: fp32-VALU version is DS-pipe bound (338 broadcast
// ds_read_b128/step + 1536 conflict cyc/step ~ 2900 DS cyc/step). The
// h-broadcast volume is invariant for VALU dot products -> restructure.
//
// This version: gates[400x2] = W_hh[400x100] @ h[100x2] via
// mfma_f32_16x16x32_bf16 with fp32 emulated by bf16 hi/lo split:
//   W.h ~ Whi.hhi + Whi.hlo + Wlo.hhi   (residual ~2^-17 rel; fp32-class)
// - M = gate rows: 25 tiles of 16.  K = 100 -> 4 tiles of 32 (zero-pad).
//   N = batch: cols 0,1 of 16 (cols 2-15 garbage, never read out).
// - 13 waves (block=832): waves 0-11 own 2 M-tiles, wave 12 owns 1 M-tile
//   + the W_out projection (phase C), pipelined one step behind.
// - W fragments: 16 short8 = 64 VGPR/wave, asm-barriered vs remat (R2),
//   sized to fit the allocator's 128-reg target (R1-R4 lesson).
// - B fragments: 8 ds_read_b128/wave/step, banks 8q+4nb+{0..3} = all 32
//   distinct -> conflict-free.
// Verified layouts (m89): A[m=lane&15][k=quad*8+j]; B[k=quad*8+j][n=lane&15];
// D[row=quad*4+reg][col=lane&15].

#define HID   100
#define TLEN  1024
#define BLOCK 832   // 13 waves

typedef __attribute__((ext_vector_type(8))) short short8;
typedef __attribute__((ext_vector_type(4))) float f32x4;

static __device__ __forceinline__ short bf16_rne(float x) {
    unsigned u = __float_as_uint(x);
    unsigned r = u + 0x7FFFu + ((u >> 16) & 1u);
    return (short)(r >> 16);
}
static __device__ __forceinline__ float bf16_dec(short s) {
    return __uint_as_float(((unsigned)(unsigned short)s) << 16);
}

__global__ __launch_bounds__(BLOCK) void lstm_mfma(
    const float* __restrict__ input,   // [B, T]
    const float* __restrict__ W_ih,    // [4H]
    const float* __restrict__ W_hh,    // [4H, H]
    const float* __restrict__ b_ih,    // [4H]
    const float* __restrict__ b_hh,    // [4H]
    const float* __restrict__ W_out,   // [H]
    const float* __restrict__ b_out,   // [1]
    float* __restrict__ out)           // [B, T]
{
    const int tid  = threadIdx.x;
    const int b0   = blockIdx.x * 2;
    const int wv   = tid >> 6;
    const int lane = tid & 63;
    const int col  = lane & 15;        // MFMA n / D col
    const int quad = lane >> 4;        // MFMA k-block / D row-block
    const int nb   = col & 1;          // batch slot to read (cols>=2: garbage ok)

    __shared__ __align__(16) float in_s[2][TLEN];    // 8 KB
    __shared__ __align__(16) float g_s[2][400];      // gates (b, row)
    __shared__ __align__(16) float h_s[2][HID];      // fp32 h for phase C
    __shared__ __align__(16) short BHi[16 * 2 * 8];  // [k8block][b][j]
    __shared__ __align__(16) short BLo[16 * 2 * 8];

    // Stage inputs (coalesced) + zero B staging (covers h0=0 and k-padding).
    for (int i = tid; i < TLEN; i += BLOCK) {
        in_s[0][i] = input[(b0 + 0) * TLEN + i];
        in_s[1][i] = input[(b0 + 1) * TLEN + i];
    }
    if (tid < 256) { BHi[tid] = 0; BLo[tid] = 0; }

    // ---- Build persistent W_hh A-fragments (hi/lo bf16), once.
    const int  mt0 = 2 * wv;               // wave 12 -> 24 (single tile)
    const bool two = (wv < 12);
    short8 wHi[2][4], wLo[2][4];
    #pragma unroll
    for (int m = 0; m < 2; ++m) {
        int mt = mt0 + m; if (mt > 24) mt = 24;   // wave 12's m=1 unused
        const int r = 16 * mt + col;              // A row m = lane&15
        #pragma unroll
        for (int kt = 0; kt < 4; ++kt) {
            short8 hi, lo;
            #pragma unroll
            for (int j = 0; j < 8; ++j) {
                const int kk = 32 * kt + 8 * quad + j;   // A k = quad*8+j
                float w = (kk < HID) ? W_hh[r * HID + kk] : 0.f;
                short h16 = bf16_rne(w);
                short l16 = bf16_rne(w - bf16_dec(h16));
                hi[j] = h16; lo[j] = l16;
            }
            wHi[m][kt] = hi; wLo[m][kt] = lo;
        }
    }
    {   // opacity barrier: forbid remat/sink of the load+cvt chain (R2 lesson)
        int* q = (int*)wHi; int* p = (int*)wLo;
        #pragma unroll
        for (int i = 0; i < 32; ++i) {
            asm volatile("" : "+v"(q[i]));
            asm volatile("" : "+v"(p[i]));
        }
    }

    // ---- Phase-B constants (threads 0..199: batch pb, unit pj)
    const int pb = (tid >= 100) ? 1 : 0;
    const int pj = (tid < 200) ? (tid - pb * 100) : 0;
    float wi[4], bi[4];
    #pragma unroll
    for (int g = 0; g < 4; ++g) {
        wi[g] = W_ih[g * 100 + pj];
        bi[g] = b_ih[g * 100 + pj] + b_hh[g * 100 + pj];
    }

    // ---- Phase-C constants (wave 12)
    float wo0 = 0.f, wo1 = 0.f, bo = 0.f;
    if (wv == 12) {
        wo0 = W_out[lane];                          // lane<64<100
        wo1 = (lane < HID - 64) ? W_out[64 + lane] : 0.f;
        bo  = b_out[0];
    }

    float c = 0.f;                                  // cell state (phase-B threads)
    __syncthreads();

    for (int t = 0; t < TLEN; ++t) {
        // ---- Phase C (wave 12): out[t-1] from h_s (= h_{t-1}); overlaps MFMA.
        if (wv == 12 && t > 0) {
            float p = h_s[0][lane] * wo0;
            float q = h_s[1][lane] * wo0;
            if (lane < HID - 64) {
                p = fmaf(h_s[0][64 + lane], wo1, p);
                q = fmaf(h_s[1][64 + lane], wo1, q);
            }
            #pragma unroll
            for (int off = 32; off > 0; off >>= 1) {
                p += __shfl_down(p, off);
                q += __shfl_down(q, off);
            }
            if (lane == 0) {
                out[(b0 + 0) * TLEN + (t - 1)] = p + bo;
                out[(b0 + 1) * TLEN + (t - 1)] = q + bo;
            }
        }

        // ---- MFMA phase: gates = W.h  (h = h_{t-1} in BHi/BLo)
        short8 bh[4], bl[4];
        #pragma unroll
        for (int kt = 0; kt < 4; ++kt) {
            const int idx = 8 * kt + 2 * quad + nb;      // short8 index
            bh[kt] = ((const short8*)BHi)[idx];
            bl[kt] = ((const short8*)BLo)[idx];
        }
        f32x4 acc0 = {0.f, 0.f, 0.f, 0.f};
        f32x4 acc1 = {0.f, 0.f, 0.f, 0.f};
        #pragma unroll
        for (int kt = 0; kt < 4; ++kt) {
            acc0 = __builtin_amdgcn_mfma_f32_16x16x32_bf16(wHi[0][kt], bh[kt], acc0, 0, 0, 0);
            acc0 = __builtin_amdgcn_mfma_f32_16x16x32_bf16(wHi[0][kt], bl[kt], acc0, 0, 0, 0);
            acc0 = __builtin_amdgcn_mfma_f32_16x16x32_bf16(wLo[0][kt], bh[kt], acc0, 0, 0, 0);
            if (two) {
                acc1 = __builtin_amdgcn_mfma_f32_16x16x32_bf16(wHi[1][kt], bh[kt], acc1, 0, 0, 0);
                acc1 = __builtin_amdgcn_mfma_f32_16x16x32_bf16(wHi[1][kt], bl[kt], acc1, 0, 0, 0);
                acc1 = __builtin_amdgcn_mfma_f32_16x16x32_bf16(wLo[1][kt], bh[kt], acc1, 0, 0, 0);
            }
        }
        // Epilogue: D rows quad*4..+3 are contiguous -> one b128 store per tile.
        if (col < 2) {
            *(f32x4*)(&g_s[col][16 * mt0 + 4 * quad]) = acc0;
            if (two) *(f32x4*)(&g_s[col][16 * (mt0 + 1) + 4 * quad]) = acc1;
        }
        __syncthreads();

        // ---- Phase B: pointwise cell (200 threads), writes h_t (fp32 + hi/lo)
        if (tid < 200) {
            const float x = in_s[pb][t];
            float ig = fmaf(x, wi[0], bi[0]) + g_s[pb][pj];
            float fg = fmaf(x, wi[1], bi[1]) + g_s[pb][100 + pj];
            float gg = fmaf(x, wi[2], bi[2]) + g_s[pb][200 + pj];
            float og = fmaf(x, wi[3], bi[3]) + g_s[pb][300 + pj];
            float is = 1.f / (1.f + __expf(-ig));
            float fs = 1.f / (1.f + __expf(-fg));
            float os = 1.f / (1.f + __expf(-og));
            float gt = 1.f - 2.f / (__expf(2.f * gg) + 1.f);   // stable tanh
            c = fmaf(fs, c, is * gt);
            float hv = os * (1.f - 2.f / (__expf(2.f * c) + 1.f));
            h_s[pb][pj] = hv;
            short h16 = bf16_rne(hv);
            short l16 = bf16_rne(hv - bf16_dec(h16));
            const int widx = ((pj >> 3) * 2 + pb) * 8 + (pj & 7);  // B[k][n] slot
            BHi[widx] = h16;
            BLo[widx] = l16;
        }
        __syncthreads();
    }

    // Final output: t = TLEN-1 (h_s holds h_{TLEN-1})
    if (wv == 12) {
        float p = h_s[0][lane] * wo0;
        float q = h_s[1][lane] * wo0;
        if (lane < HID - 64) {
            p = fmaf(h_s[0][64 + lane], wo1, p);
            q = fmaf(h_s[1][64 + lane], wo1, q);
        }
        #pragma unroll
        for (int off = 32; off > 0; off >>= 1) {
            p += __shfl_down(p, off);
            q += __shfl_down(q, off);
        }
        if (lane == 0) {
            out[(b0 + 0) * TLEN + (TLEN - 1)] = p + bo;
            out[(b0 + 1) * TLEN + (TLEN - 1)] = q + bo;
        }
    }
}

extern "C" void kernel_launch(void* const* d_in, const int* in_sizes, int n_in,
                              void* d_out, int out_size, void* d_ws, size_t ws_size,
                              hipStream_t stream) {
    const float* input = (const float*)d_in[0];
    const float* W_ih  = (const float*)d_in[1];
    const float* W_hh  = (const float*)d_in[2];
    const float* b_ih  = (const float*)d_in[3];
    const float* b_hh  = (const float*)d_in[4];
    const float* W_out = (const float*)d_in[5];
    const float* b_out = (const float*)d_in[6];
    float* out = (float*)d_out;

    const int B = in_sizes[0] / TLEN;  // 512
    lstm_mfma<<<B / 2, BLOCK, 0, stream>>>(input, W_ih, W_hh, b_ih, b_hh,
                                           W_out, b_out, out);
}

// Round 7
// 1277.720 us; speedup vs baseline: 1.1874x; 1.1874x over previous
//
#include <hip/hip_runtime.h>

// LSTM, B=512 x T=1024, H=100, input_size=1.  MFMA persistent-RNN, v2.
//
// R6 post-mortem: 13 waves each re-read the SAME 256 B of B-fragments
// (8 ds_read_b128/wave/step, ~12 cyc each RF-write-bound) -> DS pipe
// ~2900 cyc/step = the whole step time. DS cost scales with WAVE COUNT,
// so: fewer, fatter waves. 7 waves (block=448): waves 0-5 hold 4 M-tiles
// of W_hh fragments (128 regs, expected in AGPRs per R6's VGPR=64 tell),
// wave 6 holds tile 24 + the W_out projection. 25 tiles, 0 dummy MFMAs.
//
// fp32-class precision via bf16 hi/lo split: W.h ~ Whi.Bhi + Whi.Blo + Wlo.Bhi.
// Verified layouts (m89): A[m=lane&15][k=quad*8+j]; B[k=quad*8+j][n=lane&15];
// D[row=quad*4+reg][col=lane&15].

#define HID   100
#define TLEN  1024
#define BLOCK 448   // 7 waves

typedef __attribute__((ext_vector_type(8))) short short8;
typedef __attribute__((ext_vector_type(4))) float f32x4;

static __device__ __forceinline__ short bf16_rne(float x) {
    unsigned u = __float_as_uint(x);
    unsigned r = u + 0x7FFFu + ((u >> 16) & 1u);
    return (short)(r >> 16);
}
static __device__ __forceinline__ float bf16_dec(short s) {
    return __uint_as_float(((unsigned)(unsigned short)s) << 16);
}

__global__ __launch_bounds__(BLOCK)
__attribute__((amdgpu_waves_per_eu(2, 2)))
void lstm_mfma7(
    const float* __restrict__ input,   // [B, T]
    const float* __restrict__ W_ih,    // [4H]
    const float* __restrict__ W_hh,    // [4H, H]
    const float* __restrict__ b_ih,    // [4H]
    const float* __restrict__ b_hh,    // [4H]
    const float* __restrict__ W_out,   // [H]
    const float* __restrict__ b_out,   // [1]
    float* __restrict__ out)           // [B, T]
{
    const int tid  = threadIdx.x;
    const int b0   = blockIdx.x * 2;
    const int wv   = tid >> 6;
    const int lane = tid & 63;
    const int col  = lane & 15;        // MFMA m (A row) / D col
    const int quad = lane >> 4;        // MFMA k-block / D row-block
    const int nb   = col & 1;          // batch slot (cols>=2 garbage, unread)
    const bool full = (wv < 6);        // waves 0-5: 4 tiles; wave 6: 1 tile

    __shared__ __align__(16) float in_s[2][TLEN];    // 8 KB
    __shared__ __align__(16) float g_s[2][448];      // gates (b, row); rows<400 used
    __shared__ __align__(16) float h_s[2][104];      // fp32 h for phase C
    __shared__ __align__(16) short BHi[16 * 2 * 8];  // [k8block][b][j]
    __shared__ __align__(16) short BLo[16 * 2 * 8];

    // Stage inputs (coalesced) + zero B staging (covers h0=0 and k-padding).
    for (int i = tid; i < TLEN; i += BLOCK) {
        in_s[0][i] = input[(b0 + 0) * TLEN + i];
        in_s[1][i] = input[(b0 + 1) * TLEN + i];
    }
    if (tid < 256) { BHi[tid] = 0; BLo[tid] = 0; }

    // ---- Build persistent W_hh A-fragments (hi/lo bf16), once.
    // wave wv<6: tiles 4wv..4wv+3; wave 6: tile 24 (m>0 slots duplicate it,
    // never used/stored). Per-fragment asm barriers: volatile asm can't be
    // sunk into the loop (R2 remat lesson) and keeps peak setup pressure low.
    short8 wHi[4][4], wLo[4][4];
    #pragma unroll
    for (int m = 0; m < 4; ++m) {
        const int mt = full ? (4 * wv + m) : 24;
        const int r  = 16 * mt + col;             // A row = lane&15
        #pragma unroll
        for (int kt = 0; kt < 4; ++kt) {
            short8 hi, lo;
            #pragma unroll
            for (int j = 0; j < 8; ++j) {
                const int kk = 32 * kt + 8 * quad + j;   // A k = quad*8+j
                float w = (kk < HID) ? W_hh[r * HID + kk] : 0.f;
                short h16 = bf16_rne(w);
                short l16 = bf16_rne(w - bf16_dec(h16));
                hi[j] = h16; lo[j] = l16;
            }
            asm volatile("" : "+v"(((int*)&hi)[0]), "+v"(((int*)&hi)[1]),
                              "+v"(((int*)&hi)[2]), "+v"(((int*)&hi)[3]));
            asm volatile("" : "+v"(((int*)&lo)[0]), "+v"(((int*)&lo)[1]),
                              "+v"(((int*)&lo)[2]), "+v"(((int*)&lo)[3]));
            wHi[m][kt] = hi; wLo[m][kt] = lo;
        }
    }

    // ---- Phase-B constants (threads 0..199: batch pb, unit pj)
    const int pb = (tid >= 100) ? 1 : 0;
    const int pj = (tid < 200) ? (tid - pb * 100) : 0;
    float wi[4], bi[4];
    #pragma unroll
    for (int g = 0; g < 4; ++g) {
        wi[g] = W_ih[g * 100 + pj];
        bi[g] = b_ih[g * 100 + pj] + b_hh[g * 100 + pj];
    }

    // ---- Phase-C constants (wave 6)
    float wo0 = 0.f, wo1 = 0.f, bo = 0.f;
    if (wv == 6) {
        wo0 = W_out[lane];                          // lane<64<100
        wo1 = (lane < HID - 64) ? W_out[64 + lane] : 0.f;
        bo  = b_out[0];
    }

    float c = 0.f;                                  // cell state (phase-B threads)
    __syncthreads();

    for (int t = 0; t < TLEN; ++t) {
        // ---- Window 1: MFMA gates = W.h_{t-1};  wave 6 also does phase C.
        if (wv == 6 && t > 0) {                     // out[t-1] from stable h_s
            float p = h_s[0][lane] * wo0;
            float q = h_s[1][lane] * wo0;
            if (lane < HID - 64) {
                p = fmaf(h_s[0][64 + lane], wo1, p);
                q = fmaf(h_s[1][64 + lane], wo1, q);
            }
            #pragma unroll
            for (int off = 32; off > 0; off >>= 1) {
                p += __shfl_down(p, off);
                q += __shfl_down(q, off);
            }
            if (lane == 0) {
                out[(b0 + 0) * TLEN + (t - 1)] = p + bo;
                out[(b0 + 1) * TLEN + (t - 1)] = q + bo;
            }
        }

        short8 bh[4], bl[4];
        #pragma unroll
        for (int kt = 0; kt < 4; ++kt) {
            const int idx = 8 * kt + 2 * quad + nb;      // short8 index
            bh[kt] = ((const short8*)BHi)[idx];
            bl[kt] = ((const short8*)BLo)[idx];
        }
        f32x4 a0 = {0,0,0,0}, a1 = {0,0,0,0}, a2 = {0,0,0,0}, a3 = {0,0,0,0};
        #pragma unroll
        for (int kt = 0; kt < 4; ++kt) {
            a0 = __builtin_amdgcn_mfma_f32_16x16x32_bf16(wHi[0][kt], bh[kt], a0, 0, 0, 0);
            a0 = __builtin_amdgcn_mfma_f32_16x16x32_bf16(wHi[0][kt], bl[kt], a0, 0, 0, 0);
            a0 = __builtin_amdgcn_mfma_f32_16x16x32_bf16(wLo[0][kt], bh[kt], a0, 0, 0, 0);
            if (full) {
                a1 = __builtin_amdgcn_mfma_f32_16x16x32_bf16(wHi[1][kt], bh[kt], a1, 0, 0, 0);
                a1 = __builtin_amdgcn_mfma_f32_16x16x32_bf16(wHi[1][kt], bl[kt], a1, 0, 0, 0);
                a1 = __builtin_amdgcn_mfma_f32_16x16x32_bf16(wLo[1][kt], bh[kt], a1, 0, 0, 0);
                a2 = __builtin_amdgcn_mfma_f32_16x16x32_bf16(wHi[2][kt], bh[kt], a2, 0, 0, 0);
                a2 = __builtin_amdgcn_mfma_f32_16x16x32_bf16(wHi[2][kt], bl[kt], a2, 0, 0, 0);
                a2 = __builtin_amdgcn_mfma_f32_16x16x32_bf16(wLo[2][kt], bh[kt], a2, 0, 0, 0);
                a3 = __builtin_amdgcn_mfma_f32_16x16x32_bf16(wHi[3][kt], bh[kt], a3, 0, 0, 0);
                a3 = __builtin_amdgcn_mfma_f32_16x16x32_bf16(wHi[3][kt], bl[kt], a3, 0, 0, 0);
                a3 = __builtin_amdgcn_mfma_f32_16x16x32_bf16(wLo[3][kt], bh[kt], a3, 0, 0, 0);
            }
        }
        // Epilogue: D rows quad*4..+3 contiguous -> one b128 store per tile.
        if (col < 2) {
            const int mt0 = full ? 4 * wv : 24;
            *(f32x4*)(&g_s[col][16 * mt0 + 4 * quad]) = a0;
            if (full) {
                *(f32x4*)(&g_s[col][16 * (mt0 + 1) + 4 * quad]) = a1;
                *(f32x4*)(&g_s[col][16 * (mt0 + 2) + 4 * quad]) = a2;
                *(f32x4*)(&g_s[col][16 * (mt0 + 3) + 4 * quad]) = a3;
            }
        }
        __syncthreads();

        // ---- Window 2: pointwise cell (200 threads), writes h_t (fp32 + hi/lo)
        if (tid < 200) {
            const float x = in_s[pb][t];
            float ig = fmaf(x, wi[0], bi[0]) + g_s[pb][pj];
            float fg = fmaf(x, wi[1], bi[1]) + g_s[pb][100 + pj];
            float gg = fmaf(x, wi[2], bi[2]) + g_s[pb][200 + pj];
            float og = fmaf(x, wi[3], bi[3]) + g_s[pb][300 + pj];
            float is = 1.f / (1.f + __expf(-ig));
            float fs = 1.f / (1.f + __expf(-fg));
            float os = 1.f / (1.f + __expf(-og));
            float gt = 1.f - 2.f / (__expf(2.f * gg) + 1.f);   // stable tanh
            c = fmaf(fs, c, is * gt);
            float hv = os * (1.f - 2.f / (__expf(2.f * c) + 1.f));
            h_s[pb][pj] = hv;
            short h16 = bf16_rne(hv);
            short l16 = bf16_rne(hv - bf16_dec(h16));
            const int widx = ((pj >> 3) * 2 + pb) * 8 + (pj & 7);  // B[k][n] slot
            BHi[widx] = h16;
            BLo[widx] = l16;
        }
        __syncthreads();
    }

    // Final output: t = TLEN-1 (h_s holds h_{TLEN-1})
    if (wv == 6) {
        float p = h_s[0][lane] * wo0;
        float q = h_s[1][lane] * wo0;
        if (lane < HID - 64) {
            p = fmaf(h_s[0][64 + lane], wo1, p);
            q = fmaf(h_s[1][64 + lane], wo1, q);
        }
        #pragma unroll
        for (int off = 32; off > 0; off >>= 1) {
            p += __shfl_down(p, off);
            q += __shfl_down(q, off);
        }
        if (lane == 0) {
            out[(b0 + 0) * TLEN + (TLEN - 1)] = p + bo;
            out[(b0 + 1) * TLEN + (TLEN - 1)] = q + bo;
        }
    }
}

extern "C" void kernel_launch(void* const* d_in, const int* in_sizes, int n_in,
                              void* d_out, int out_size, void* d_ws, size_t ws_size,
                              hipStream_t stream) {
    const float* input = (const float*)d_in[0];
    const float* W_ih  = (const float*)d_in[1];
    const float* W_hh  = (const float*)d_in[2];
    const float* b_ih  = (const float*)d_in[3];
    const float* b_hh  = (const float*)d_in[4];
    const float* W_out = (const float*)d_in[5];
    const float* b_out = (const float*)d_in[6];
    float* out = (float*)d_out;

    const int B = in_sizes[0] / TLEN;  // 512
    lstm_mfma7<<<B / 2, BLOCK, 0, stream>>>(input, W_ih, W_hh, b_ih, b_hh,
                                            W_out, b_out, out);
}